// Round 4
// baseline (512.841 us; speedup 1.0000x reference)
//
#include <hip/hip_runtime.h>
#include <hip/hip_bf16.h>
#include <math.h>

#define Bn 256
#define Mn 196
#define Dn 512
#define Mstr 232      // LDS col stride (shorts): 464B = 29 x 16B granules -> spread banks for b128
#define TILE 128
#define OUTB 131328   // 512*513/2

typedef __attribute__((ext_vector_type(8))) short bf16x8;
typedef __attribute__((ext_vector_type(4))) float f32x4;

__device__ __forceinline__ unsigned pack2(float a, float b) {
  __hip_bfloat16 ha = __float2bfloat16(a);
  __hip_bfloat16 hb = __float2bfloat16(b);
  unsigned short lo = *reinterpret_cast<unsigned short*>(&ha);
  unsigned short hi = *reinterpret_cast<unsigned short*>(&hb);
  return ((unsigned)hi << 16) | (unsigned)lo;
}

// One block per batch. Pass A: all 10 tile-pairs -> rowsums in LDS.
// Pass B: recompute pairs (reversed buffer schedule), write centered output.
__global__ __launch_bounds__(1024)
void k1_fused(const float* __restrict__ x, const float* __restrict__ tptr,
              float* __restrict__ out) {
  __shared__ short bufA[TILE * Mstr];
  __shared__ short bufB[TILE * Mstr];
  __shared__ float dtmp[1024];
  __shared__ float dAll[512];
  __shared__ float rowsumL[512];
  __shared__ float totL;

  const int tid = threadIdx.x;
  const int b = blockIdx.x;
  const float* xb = x + (size_t)b * Mn * Dn;
  const float et = expf(tptr[0]);
  const size_t outb = (size_t)b * OUTB;

  const int lane = tid & 63;
  const int wid  = tid >> 6;               // 0..15
  const int wi = wid >> 2, wj = wid & 3;   // 4x4 waves of 32x32
  const int lr = lane & 15, lg = lane >> 4;
  const int c = tid & 127;                 // panel column
  const int w = tid >> 7;                  // m-chunk phase 0..7

  if (tid < 512) rowsumL[tid] = 0.f;

  float xv[4][8];   // prefetched panel slice (issued early, consumed in pstore)

  auto pload = [&](int c0) {
    #pragma unroll
    for (int it = 0; it < 4; ++it) {
      const int mc = w + 8 * it;
      #pragma unroll
      for (int u = 0; u < 8; ++u) {
        const int m = mc * 8 + u;
        xv[it][u] = (mc < 28 && m < Mn) ? xb[(size_t)m * Dn + c0 + c] : 0.f;
      }
    }
  };

  auto pstore = [&](short* buf, int pan, bool dg) {
    __syncthreads();                       // readers of this buffer are done
    float dacc = 0.f;
    #pragma unroll
    for (int it = 0; it < 4; ++it) {
      const int mc = w + 8 * it;
      if (mc < 28) {
        if (dg) {
          #pragma unroll
          for (int u = 0; u < 8; ++u) dacc += xv[it][u] * xv[it][u];
        }
        uint4 pk;
        pk.x = pack2(xv[it][0], xv[it][1]);
        pk.y = pack2(xv[it][2], xv[it][3]);
        pk.z = pack2(xv[it][4], xv[it][5]);
        pk.w = pack2(xv[it][6], xv[it][7]);
        *reinterpret_cast<uint4*>(&buf[c * Mstr + mc * 8]) = pk;
      }
    }
    if (dg) dtmp[tid] = dacc;
    __syncthreads();                       // panel visible to all
    if (dg) {
      if (tid < 128) {
        float s = 0.f;
        #pragma unroll
        for (int p = 0; p < 8; ++p) s += dtmp[p * 128 + tid];
        dAll[pan * 128 + tid] = s;
      }
      __syncthreads();
    }
  };

  auto cpair = [&](int ti, int tj, const short* bI, const short* bJ,
                   bool passB, float ctot) {
    const float* dI = dAll + ti * TILE;
    const float* dJ = dAll + tj * TILE;
    f32x4 acc[2][2];
    #pragma unroll
    for (int a = 0; a < 2; ++a)
      #pragma unroll
      for (int cc = 0; cc < 2; ++cc) acc[a][cc] = (f32x4){0.f, 0.f, 0.f, 0.f};

    #pragma unroll
    for (int kk = 0; kk < 7; ++kk) {
      const int k0 = kk * 32 + lg * 8;
      bf16x8 af[2], bfv[2];
      #pragma unroll
      for (int mi = 0; mi < 2; ++mi)
        af[mi] = *reinterpret_cast<const bf16x8*>(&bI[(wi * 32 + mi * 16 + lr) * Mstr + k0]);
      #pragma unroll
      for (int nj = 0; nj < 2; ++nj)
        bfv[nj] = *reinterpret_cast<const bf16x8*>(&bJ[(wj * 32 + nj * 16 + lr) * Mstr + k0]);
      #pragma unroll
      for (int mi = 0; mi < 2; ++mi)
        #pragma unroll
        for (int nj = 0; nj < 2; ++nj)
          acc[mi][nj] = __builtin_amdgcn_mfma_f32_16x16x32_bf16(af[mi], bfv[nj], acc[mi][nj], 0, 0, 0);
    }

    float colAcc[2] = {0.f, 0.f};
    #pragma unroll
    for (int mi = 0; mi < 2; ++mi) {
      #pragma unroll
      for (int reg = 0; reg < 4; ++reg) {
        const int iloc = wi * 32 + mi * 16 + lg * 4 + reg;
        const int ig = ti * TILE + iloc;
        float rowAcc = 0.f;
        #pragma unroll
        for (int nj = 0; nj < 2; ++nj) {
          const int jloc = wj * 32 + nj * 16 + lr;
          const int jg = tj * TILE + jloc;
          float g = acc[mi][nj][reg];
          float raw = dI[iloc] + dJ[jloc] - 2.f * g;
          raw = fmaxf(raw, 0.f);
          if (ig == jg) raw = 0.f;          // exact-0 diagonal (matches reference)
          const float v = sqrtf(et * raw + 1e-5f);
          if (!passB) {
            if (ig <= jg) rowAcc += v;      // row i: all j>=i (non-self pairs: always)
            if (ig <  jg) colAcc[nj] += v;  // col j: strict upper (symmetric twin)
          } else if (ig <= jg) {
            const float wv = v - (rowsumL[ig] + rowsumL[jg]) * (1.f / 512.f) + ctot;
            out[outb + ig * Dn - (ig * (ig - 1)) / 2 + (jg - ig)] = wv;
          }
        }
        if (!passB) {
          rowAcc += __shfl_xor(rowAcc, 1);
          rowAcc += __shfl_xor(rowAcc, 2);
          rowAcc += __shfl_xor(rowAcc, 4);
          rowAcc += __shfl_xor(rowAcc, 8);
          if (lr == 0) atomicAdd(&rowsumL[ig], rowAcc);
        }
      }
    }
    if (!passB) {
      #pragma unroll
      for (int nj = 0; nj < 2; ++nj) {
        float cs = colAcc[nj];
        cs += __shfl_xor(cs, 16);
        cs += __shfl_xor(cs, 32);
        if (lg == 0) atomicAdd(&rowsumL[tj * TILE + wj * 32 + nj * 16 + lr], cs);
      }
    }
  };

  // ---------------- pass A: rowsums ----------------
  pload(0);                       pstore(bufA, 0, true);
  pload(128);                     pstore(bufB, 1, true);
  pload(256);
  cpair(0,0,bufA,bufA,false,0.f); cpair(0,1,bufA,bufB,false,0.f); cpair(1,1,bufB,bufB,false,0.f);
  pstore(bufB, 2, true);
  pload(384);
  cpair(0,2,bufA,bufB,false,0.f); cpair(2,2,bufB,bufB,false,0.f);
  pstore(bufB, 3, true);
  pload(128);
  cpair(0,3,bufA,bufB,false,0.f); cpair(3,3,bufB,bufB,false,0.f);
  pstore(bufA, 1, false);
  pload(256);
  cpair(1,3,bufA,bufB,false,0.f);
  pstore(bufB, 2, false);
  pload(384);
  cpair(1,2,bufA,bufB,false,0.f);
  pstore(bufA, 3, false);
  cpair(2,3,bufB,bufA,false,0.f);

  // ---------------- total reduce ----------------
  __syncthreads();
  if (tid < 512) {
    float v = rowsumL[tid];
    #pragma unroll
    for (int m = 1; m < 64; m <<= 1) v += __shfl_xor(v, m);
    if ((tid & 63) == 0) dtmp[tid >> 6] = v;
  }
  __syncthreads();
  if (tid == 0) {
    float s = 0.f;
    #pragma unroll
    for (int i = 0; i < 8; ++i) s += dtmp[i];
    totL = s;
  }
  __syncthreads();
  const float ctot = totL * (1.f / (512.f * 512.f));

  // ---------------- pass B: centered write (reversed schedule) ----------------
  // state entering: A=panel3, B=panel2
  pload(128);
  cpair(2,3,bufB,bufA,true,ctot);
  pstore(bufA, 1, false);
  pload(384);
  cpair(1,2,bufA,bufB,true,ctot);
  pstore(bufB, 3, false);
  pload(0);
  cpair(1,3,bufA,bufB,true,ctot);
  pstore(bufA, 0, false);
  pload(256);
  cpair(0,3,bufA,bufB,true,ctot); cpair(3,3,bufB,bufB,true,ctot);
  pstore(bufB, 2, false);
  pload(128);
  cpair(0,2,bufA,bufB,true,ctot); cpair(2,2,bufB,bufB,true,ctot);
  pstore(bufB, 1, false);
  cpair(0,0,bufA,bufA,true,ctot); cpair(0,1,bufA,bufB,true,ctot); cpair(1,1,bufB,bufB,true,ctot);
}

extern "C" void kernel_launch(void* const* d_in, const int* in_sizes, int n_in,
                              void* d_out, int out_size, void* d_ws, size_t ws_size,
                              hipStream_t stream) {
  const float* x = (const float*)d_in[0];
  const float* t = (const float*)d_in[1];
  float* out = (float*)d_out;
  hipLaunchKernelGGL(k1_fused, dim3(Bn), dim3(1024), 0, stream, x, t, out);
}